// Round 1
// baseline (2150.574 us; speedup 1.0000x reference)
//
#include <hip/hip_runtime.h>
#include <hip/hip_bf16.h>
#include <float.h>
#include <math.h>

#define BB 4
#define N1 4096
#define NT 8192
#define CH 128
#define NBRS 18

// ---------------------------------------------------------------- transpose
__global__ __launch_bounds__(256) void transpose_k(const float* __restrict__ in,
                                                   float* __restrict__ out,
                                                   int rows, int cols) {
  int t = blockIdx.x * 256 + threadIdx.x;
  if (t < rows * cols) {
    int r = t / cols, c = t % cols;
    out[c * rows + r] = in[t];
  }
}

// ------------------------------------------------- concat x,y + squared norms
__global__ __launch_bounds__(256) void norms_concat_k(const float* __restrict__ x,
                                                      const float* __restrict__ y,
                                                      float* __restrict__ xy,
                                                      float* __restrict__ norms) {
  int w = (blockIdx.x * 256 + threadIdx.x) >> 6;  // global point id, 0..32767
  int lane = threadIdx.x & 63;
  int b = w >> 13, row = w & 8191;
  const float* src = (row < N1) ? (x + ((size_t)b * N1 + row) * CH)
                                : (y + ((size_t)b * N1 + (row - N1)) * CH);
  float2 v = *(const float2*)(src + lane * 2);
  *(float2*)(xy + (size_t)w * CH + lane * 2) = v;
  float s = v.x * v.x + v.y * v.y;
  for (int off = 32; off > 0; off >>= 1) s += __shfl_down(s, off);
  if (lane == 0) norms[w] = s;
}

// ---------------------------------------------------------------- knn (top-9)
// grid: (16 query tiles, 2 candidate halves, 16 = b*4+combo), block 256.
// combo: 0=xx 1=xy 2=yy 3=yx. Ranks by cn - 2*dot (query norm is a per-query
// constant -> ranking-invariant). Candidates scanned in ascending index order
// with strict '<' insertion == jax.lax.top_k stable tie-break.
__global__ __launch_bounds__(256) void knn_k(const float* __restrict__ xy,
                                             const float* __restrict__ norms,
                                             float* __restrict__ pd,
                                             int* __restrict__ pi) {
  __shared__ float sc[64 * 128];
  __shared__ float sn[64];
  const int tid = threadIdx.x;
  const int qt = blockIdx.x, half = blockIdx.y, z = blockIdx.z;
  const int b = z >> 2, combo = z & 3;
  const int qoff = (combo <= 1) ? 0 : N1;
  const int coff = (combo == 0 || combo == 3) ? 0 : N1;
  const int q = qt * 256 + tid;
  const float* qrow = xy + ((size_t)b * NT + qoff + q) * CH;

  float qv[128];
#pragma unroll
  for (int k = 0; k < 32; ++k) {
    float4 v = *(const float4*)(qrow + k * 4);
    qv[4 * k] = v.x; qv[4 * k + 1] = v.y; qv[4 * k + 2] = v.z; qv[4 * k + 3] = v.w;
  }
  float bd[9]; int bi[9];
#pragma unroll
  for (int j = 0; j < 9; ++j) { bd[j] = FLT_MAX; bi[j] = 0; }

  const int cbase = half * 2048;
  for (int c0 = cbase; c0 < cbase + 2048; c0 += 64) {
    __syncthreads();
    const float* gsrc = xy + ((size_t)b * NT + coff + c0) * CH;
    for (int i = tid; i < 2048; i += 256) {
      float4 v = *(const float4*)(gsrc + i * 4);
      *(float4*)(sc + i * 4) = v;
    }
    if (tid < 64) sn[tid] = norms[(size_t)b * NT + coff + c0 + tid];
    __syncthreads();
    for (int cc = 0; cc < 64; ++cc) {
      const float* cp = sc + cc * 128;
      float a0 = 0.f, a1 = 0.f, a2 = 0.f, a3 = 0.f;
#pragma unroll
      for (int k = 0; k < 32; ++k) {
        float4 cv = *(const float4*)(cp + k * 4);
        a0 = fmaf(qv[4 * k], cv.x, a0);
        a1 = fmaf(qv[4 * k + 1], cv.y, a1);
        a2 = fmaf(qv[4 * k + 2], cv.z, a2);
        a3 = fmaf(qv[4 * k + 3], cv.w, a3);
      }
      float d = sn[cc] - 2.0f * ((a0 + a1) + (a2 + a3));
      if (d < bd[8]) {
        float nd = d; int ni = c0 + cc;
#pragma unroll
        for (int j = 0; j < 9; ++j) {
          bool sw = nd < bd[j];
          float td = bd[j]; int ti = bi[j];
          bd[j] = sw ? nd : td; bi[j] = sw ? ni : ti;
          nd = sw ? td : nd;   ni = sw ? ti : ni;
        }
      }
    }
  }
  size_t base = (((size_t)z * N1 + q) * 2 + half) * 9;
#pragma unroll
  for (int j = 0; j < 9; ++j) { pd[base + j] = bd[j]; pi[base + j] = bi[j]; }
}

// ------------------------------------------------------- merge the two halves
__global__ __launch_bounds__(256) void merge_k(const float* __restrict__ pd,
                                               const int* __restrict__ pi,
                                               int* __restrict__ nbr) {
  int t = blockIdx.x * 256 + threadIdx.x;  // 65536 = 16 * 4096
  int q = t & (N1 - 1); int z = t >> 12;
  int b = z >> 2, combo = z & 3;
  size_t abase = (((size_t)z * N1 + q) * 2 + 0) * 9;
  size_t bbase = abase + 9;
  int row = (combo <= 1) ? q : (N1 + q);
  int slot = (combo == 0 || combo == 2) ? 0 : 9;
  int ioff = (combo == 1 || combo == 2) ? N1 : 0;
  int* dst = nbr + ((size_t)b * NT + row) * NBRS + slot;
  int ia = 0, ib = 0;
  for (int s = 0; s < 9; ++s) {
    float da = (ia < 9) ? pd[abase + ia] : FLT_MAX;
    float db = (ib < 9) ? pd[bbase + ib] : FLT_MAX;
    bool ta = (da <= db);  // tie -> half 0 (smaller index) like stable top_k
    int idx = ta ? pi[abase + ia] : pi[bbase + ib];
    dst[s] = idx + ioff;
    if (ta) ++ia; else ++ib;
  }
}

// ------------------------------------------- mrconv: gather+max+linear+BN+gelu
__global__ __launch_bounds__(256) void mrconv_k(const float* __restrict__ in,
                                                const int* __restrict__ nbr,
                                                const float* __restrict__ Wt,
                                                const float* __restrict__ bias,
                                                const float* __restrict__ gam,
                                                const float* __restrict__ bet,
                                                const float* __restrict__ mean,
                                                const float* __restrict__ var,
                                                float* __restrict__ out) {
  __shared__ float h[32][260];
  const int tid = threadIdx.x;
  const int pt0 = blockIdx.x * 32;
  {
    const int w = tid >> 6, lane = tid & 63;
    for (int pp = 0; pp < 8; ++pp) {
      const int p = w * 8 + pp;
      const int n = pt0 + p;
      const int b = n >> 13;
      const float* frow = in + (size_t)n * CH;
      float2 f2 = *(const float2*)(frow + lane * 2);
      float mx = -FLT_MAX, my = -FLT_MAX;
      const int* nb = nbr + (size_t)n * NBRS;
      for (int j = 0; j < NBRS; ++j) {
        int idx = nb[j];
        const float* vrow = in + ((size_t)b * NT + idx) * CH;
        float2 v2 = *(const float2*)(vrow + lane * 2);
        mx = fmaxf(mx, v2.x - f2.x);
        my = fmaxf(my, v2.y - f2.y);
      }
      h[p][lane * 4 + 0] = f2.x; h[p][lane * 4 + 1] = mx;
      h[p][lane * 4 + 2] = f2.y; h[p][lane * 4 + 3] = my;
    }
  }
  __syncthreads();
  const int o = tid & 127, gg = tid >> 7;
  float acc[16];
#pragma unroll
  for (int p = 0; p < 16; ++p) acc[p] = 0.f;
  for (int k = 0; k < 256; k += 4) {
    float w0 = Wt[(k + 0) * CH + o], w1 = Wt[(k + 1) * CH + o];
    float w2 = Wt[(k + 2) * CH + o], w3 = Wt[(k + 3) * CH + o];
#pragma unroll
    for (int p = 0; p < 16; ++p) {
      float4 hv = *(const float4*)&h[gg * 16 + p][k];
      acc[p] = fmaf(hv.x, w0, acc[p]);
      acc[p] = fmaf(hv.y, w1, acc[p]);
      acc[p] = fmaf(hv.z, w2, acc[p]);
      acc[p] = fmaf(hv.w, w3, acc[p]);
    }
  }
  const float sc = gam[o] / sqrtf(var[o] + 1e-5f);
  const float bs = bias[o], mo = mean[o], be = bet[o];
#pragma unroll
  for (int p = 0; p < 16; ++p) {
    const int n = pt0 + gg * 16 + p;
    float hv = acc[p] + bs;
    float bn = (hv - mo) * sc + be;
    float gl = 0.5f * bn * (1.0f + erff(bn * 0.70710678118654752f));
    out[(size_t)n * CH + o] = gl + h[gg * 16 + p][2 * o];
  }
}

// -------------------------------------------------------- fc: linear+BN+res
__global__ __launch_bounds__(256) void fc_k(const float* __restrict__ in,
                                            const float* __restrict__ Wt,
                                            const float* __restrict__ bias,
                                            const float* __restrict__ gam,
                                            const float* __restrict__ bet,
                                            const float* __restrict__ mean,
                                            const float* __restrict__ var,
                                            const float* __restrict__ xres,
                                            const float* __restrict__ yres,
                                            float* __restrict__ out) {
  __shared__ float s[32][132];
  const int tid = threadIdx.x;
  const int pt0 = blockIdx.x * 32;
  {
    const int w = tid >> 6, lane = tid & 63;
    for (int pp = 0; pp < 8; ++pp) {
      const int p = w * 8 + pp, n = pt0 + p;
      float2 v = *(const float2*)(in + (size_t)n * CH + lane * 2);
      s[p][lane * 2] = v.x; s[p][lane * 2 + 1] = v.y;
    }
  }
  __syncthreads();
  const int o = tid & 127, gg = tid >> 7;
  float acc[16];
#pragma unroll
  for (int p = 0; p < 16; ++p) acc[p] = 0.f;
  for (int k = 0; k < 128; k += 4) {
    float w0 = Wt[(k + 0) * CH + o], w1 = Wt[(k + 1) * CH + o];
    float w2 = Wt[(k + 2) * CH + o], w3 = Wt[(k + 3) * CH + o];
#pragma unroll
    for (int p = 0; p < 16; ++p) {
      float4 hv = *(const float4*)&s[gg * 16 + p][k];
      acc[p] = fmaf(hv.x, w0, fmaf(hv.y, w1, fmaf(hv.z, w2, fmaf(hv.w, w3, acc[p]))));
    }
  }
  const float sc = gam[o] / sqrtf(var[o] + 1e-5f);
  const float bs = bias[o], mo = mean[o], be = bet[o];
#pragma unroll
  for (int p = 0; p < 16; ++p) {
    const int n = pt0 + gg * 16 + p;
    const int b = n >> 13, row = n & 8191;
    float bn = (acc[p] + bs - mo) * sc + be;
    float res = (row < N1) ? xres[((size_t)b * N1 + row) * CH + o]
                           : yres[((size_t)b * N1 + row - N1) * CH + o];
    out[(size_t)n * CH + o] = bn + res;
  }
}

// ----------------------------------------------- ffn: 128->512->128 fused
__global__ __launch_bounds__(256) void ffn_k(const float* __restrict__ u,
                                             const float* __restrict__ W1t,
                                             const float* __restrict__ b1,
                                             const float* __restrict__ g1,
                                             const float* __restrict__ be1,
                                             const float* __restrict__ m1,
                                             const float* __restrict__ v1,
                                             const float* __restrict__ W2t,
                                             const float* __restrict__ b2,
                                             const float* __restrict__ g2,
                                             const float* __restrict__ be2,
                                             const float* __restrict__ m2,
                                             const float* __restrict__ v2,
                                             const float* __restrict__ xmask,
                                             const float* __restrict__ ymask,
                                             float* __restrict__ outbuf) {
  __shared__ float su[16][132];
  __shared__ float h1[16][516];
  const int tid = threadIdx.x;
  const int pt0 = blockIdx.x * 16;
  {
    const int w = tid >> 6, lane = tid & 63;
    for (int pp = 0; pp < 4; ++pp) {
      const int p = w * 4 + pp, n = pt0 + p;
      float2 v = *(const float2*)(u + (size_t)n * CH + lane * 2);
      su[p][lane * 2] = v.x; su[p][lane * 2 + 1] = v.y;
    }
  }
  __syncthreads();
  {
    const int o2 = tid;  // outputs o2 and o2+256
    float a1[16], a2[16];
#pragma unroll
    for (int p = 0; p < 16; ++p) { a1[p] = 0.f; a2[p] = 0.f; }
    for (int k = 0; k < 128; k += 2) {
      float wA0 = W1t[(k + 0) * 512 + o2], wB0 = W1t[(k + 0) * 512 + o2 + 256];
      float wA1 = W1t[(k + 1) * 512 + o2], wB1 = W1t[(k + 1) * 512 + o2 + 256];
#pragma unroll
      for (int p = 0; p < 16; ++p) {
        float2 uv = *(const float2*)&su[p][k];
        a1[p] = fmaf(uv.x, wA0, fmaf(uv.y, wA1, a1[p]));
        a2[p] = fmaf(uv.x, wB0, fmaf(uv.y, wB1, a2[p]));
      }
    }
    float scA = g1[o2] / sqrtf(v1[o2] + 1e-5f);
    float scB = g1[o2 + 256] / sqrtf(v1[o2 + 256] + 1e-5f);
    float bsA = b1[o2], moA = m1[o2], beA = be1[o2];
    float bsB = b1[o2 + 256], moB = m1[o2 + 256], beB = be1[o2 + 256];
#pragma unroll
    for (int p = 0; p < 16; ++p) {
      float hA = (a1[p] + bsA - moA) * scA + beA;
      float hB = (a2[p] + bsB - moB) * scB + beB;
      h1[p][o2] = 0.5f * hA * (1.0f + erff(hA * 0.70710678118654752f));
      h1[p][o2 + 256] = 0.5f * hB * (1.0f + erff(hB * 0.70710678118654752f));
    }
  }
  __syncthreads();
  const int o = tid & 127, gg = tid >> 7;
  float acc[8];
#pragma unroll
  for (int p = 0; p < 8; ++p) acc[p] = 0.f;
  for (int k = 0; k < 512; k += 4) {
    float w0 = W2t[(k + 0) * CH + o], w1 = W2t[(k + 1) * CH + o];
    float w2 = W2t[(k + 2) * CH + o], w3 = W2t[(k + 3) * CH + o];
#pragma unroll
    for (int p = 0; p < 8; ++p) {
      float4 hv = *(const float4*)&h1[gg * 8 + p][k];
      acc[p] = fmaf(hv.x, w0, fmaf(hv.y, w1, fmaf(hv.z, w2, fmaf(hv.w, w3, acc[p]))));
    }
  }
  const float sc = g2[o] / sqrtf(v2[o] + 1e-5f);
  const float bs = b2[o], mo = m2[o], be = be2[o];
#pragma unroll
  for (int p = 0; p < 8; ++p) {
    const int n = pt0 + gg * 8 + p;
    const int b = n >> 13, row = n & 8191;
    float bn = (acc[p] + bs - mo) * sc + be;
    float gl = 0.5f * bn * (1.0f + erff(bn * 0.70710678118654752f));
    float res = su[gg * 8 + p][o];
    float msk; size_t oidx;
    if (row < N1) {
      msk = xmask[(size_t)b * N1 + row];
      oidx = ((size_t)b * N1 + row) * CH + o;
    } else {
      msk = ymask[(size_t)b * N1 + row - N1];
      oidx = (size_t)BB * N1 * CH + ((size_t)b * N1 + row - N1) * CH + o;
    }
    outbuf[oidx] = (gl + res) * msk;
  }
}

// ---------------------------------------------------------------------------
extern "C" void kernel_launch(void* const* d_in, const int* in_sizes, int n_in,
                              void* d_out, int out_size, void* d_ws, size_t ws_size,
                              hipStream_t stream) {
  const float* x  = (const float*)d_in[0];
  const float* y  = (const float*)d_in[1];
  const float* xm = (const float*)d_in[2];
  const float* ym = (const float*)d_in[3];
  // specs: mr0(4..9) mr1(10..15) fc(16..21) f1(22..27) f2(28..33); each W,b,g,beta,m,v
  const float* mr0W = (const float*)d_in[4];
  const float* mr1W = (const float*)d_in[10];
  const float* fcW  = (const float*)d_in[16];
  const float* f1W  = (const float*)d_in[22];
  const float* f2W  = (const float*)d_in[28];

  char* ws = (char*)d_ws;
  float* xyA   = (float*)(ws + 0);          // 16 MB
  float* xyB   = (float*)(ws + 16777216);   // 16 MB
  float* norms = (float*)(ws + 33554432);   // 128 KB
  float* pd    = (float*)(ws + 33685504);   // 4.5 MB
  int*   pi    = (int*)  (ws + 38404096);   // 4.5 MB
  int*   nbr   = (int*)  (ws + 43122688);   // 2.25 MB
  float* mr0t  = (float*)(ws + 45481984);   // 128 KB
  float* mr1t  = (float*)(ws + 45613056);   // 128 KB
  float* fct   = (float*)(ws + 45744128);   // 64 KB
  float* f1t   = (float*)(ws + 45809664);   // 256 KB
  float* f2t   = (float*)(ws + 46071808);   // 256 KB

  transpose_k<<<(128 * 256 + 255) / 256, 256, 0, stream>>>(mr0W, mr0t, 128, 256);
  transpose_k<<<(128 * 256 + 255) / 256, 256, 0, stream>>>(mr1W, mr1t, 128, 256);
  transpose_k<<<(128 * 128 + 255) / 256, 256, 0, stream>>>(fcW, fct, 128, 128);
  transpose_k<<<(512 * 128 + 255) / 256, 256, 0, stream>>>(f1W, f1t, 512, 128);
  transpose_k<<<(128 * 512 + 255) / 256, 256, 0, stream>>>(f2W, f2t, 128, 512);

  norms_concat_k<<<8192, 256, 0, stream>>>(x, y, xyA, norms);
  knn_k<<<dim3(16, 2, 16), 256, 0, stream>>>(xyA, norms, pd, pi);
  merge_k<<<256, 256, 0, stream>>>(pd, pi, nbr);

  mrconv_k<<<1024, 256, 0, stream>>>(xyA, nbr, mr0t,
      (const float*)d_in[5], (const float*)d_in[6], (const float*)d_in[7],
      (const float*)d_in[8], (const float*)d_in[9], xyB);
  mrconv_k<<<1024, 256, 0, stream>>>(xyB, nbr, mr1t,
      (const float*)d_in[11], (const float*)d_in[12], (const float*)d_in[13],
      (const float*)d_in[14], (const float*)d_in[15], xyA);

  fc_k<<<1024, 256, 0, stream>>>(xyA, fct,
      (const float*)d_in[17], (const float*)d_in[18], (const float*)d_in[19],
      (const float*)d_in[20], (const float*)d_in[21], x, y, xyB);

  ffn_k<<<2048, 256, 0, stream>>>(xyB,
      f1t, (const float*)d_in[23], (const float*)d_in[24], (const float*)d_in[25],
      (const float*)d_in[26], (const float*)d_in[27],
      f2t, (const float*)d_in[29], (const float*)d_in[30], (const float*)d_in[31],
      (const float*)d_in[32], (const float*)d_in[33],
      xm, ym, (float*)d_out);
}

// Round 3
// 1587.073 us; speedup vs baseline: 1.3551x; 1.3551x over previous
//
#include <hip/hip_runtime.h>
#include <hip/hip_bf16.h>
#include <float.h>
#include <math.h>

#define BB 4
#define N1 4096
#define NT 8192
#define CH 128
#define NBRS 18
#define GAP 2.0e-2f

typedef __attribute__((ext_vector_type(8))) short s16x8;
typedef __attribute__((ext_vector_type(16))) float f32x16;

__device__ inline unsigned short f2bf(float v) {
  unsigned u = __float_as_uint(v);
  unsigned r = (u + 0x7FFFu + ((u >> 16) & 1u)) >> 16;
  return (unsigned short)r;
}

// ---------------------------------------------------------------- transpose
__global__ __launch_bounds__(256) void transpose_k(const float* __restrict__ in,
                                                   float* __restrict__ out,
                                                   int rows, int cols) {
  int t = blockIdx.x * 256 + threadIdx.x;
  if (t < rows * cols) {
    int r = t / cols, c = t % cols;
    out[c * rows + r] = in[t];
  }
}

// ------------------------------------------------- concat x,y + squared norms
__global__ __launch_bounds__(256) void norms_concat_k(const float* __restrict__ x,
                                                      const float* __restrict__ y,
                                                      float* __restrict__ xy,
                                                      float* __restrict__ norms) {
  int w = (blockIdx.x * 256 + threadIdx.x) >> 6;  // global point id, 0..32767
  int lane = threadIdx.x & 63;
  int b = w >> 13, row = w & 8191;
  const float* src = (row < N1) ? (x + ((size_t)b * N1 + row) * CH)
                                : (y + ((size_t)b * N1 + (row - N1)) * CH);
  float2 v = *(const float2*)(src + lane * 2);
  *(float2*)(xy + (size_t)w * CH + lane * 2) = v;
  float s = v.x * v.x + v.y * v.y;
  for (int off = 32; off > 0; off >>= 1) s += __shfl_down(s, off);
  if (lane == 0) norms[w] = s;
}

// ---------------------------------------- build split-bf16 k-major candidate buf
__global__ __launch_bounds__(256) void cbt_k(const float* __restrict__ xy,
                                             unsigned short* __restrict__ cbt) {
  int t = blockIdx.x * 256 + threadIdx.x;  // 32768*16
  int u = t >> 15, p = t & 32767;
  const float* src = xy + (size_t)p * CH + u * 8;
  unsigned hw[4], lw[4];
#pragma unroll
  for (int j = 0; j < 4; ++j) {
    float v0 = src[2 * j], v1 = src[2 * j + 1];
    unsigned short h0 = f2bf(v0), h1 = f2bf(v1);
    float r0 = v0 - __uint_as_float((unsigned)h0 << 16);
    float r1 = v1 - __uint_as_float((unsigned)h1 << 16);
    unsigned short l0 = f2bf(r0), l1 = f2bf(r1);
    hw[j] = (unsigned)h0 | ((unsigned)h1 << 16);
    lw[j] = (unsigned)l0 | ((unsigned)l1 << 16);
  }
  *(uint4*)&cbt[((size_t)u * 32768 + p) * 8] = make_uint4(hw[0], hw[1], hw[2], hw[3]);
  *(uint4*)&cbt[((size_t)(u + 16) * 32768 + p) * 8] = make_uint4(lw[0], lw[1], lw[2], lw[3]);
}

#define INSERT12(bd, bi, nd0, ni0)                        \
  {                                                       \
    float nd = nd0; int ni = ni0;                         \
    _Pragma("unroll")                                     \
    for (int j = 0; j < 12; ++j) {                        \
      bool sw = nd < bd[j];                               \
      float td = bd[j]; int ti = bi[j];                   \
      bd[j] = sw ? nd : td; bi[j] = sw ? ni : ti;         \
      nd = sw ? td : nd; ni = sw ? ti : ni;               \
    }                                                     \
  }

// ------------------------------------------------ MFMA knn: approx top-12 x 2
__global__ __launch_bounds__(256) void knn2_k(const unsigned short* __restrict__ cbt,
                                              const float* __restrict__ norms,
                                              float* __restrict__ plD,
                                              unsigned short* __restrict__ plI) {
  __shared__ unsigned short __align__(16) cst[2][32][32][8];
  __shared__ float cnl[4096];
  const int tid = threadIdx.x;
  const int qblk = blockIdx.x, z = blockIdx.y;
  const int b = z >> 2, combo = z & 3;
  const int qoff = (combo <= 1) ? 0 : N1;
  const int coff = (combo == 0 || combo == 3) ? 0 : N1;
  const int w = tid >> 6;
  const int cl = tid & 31;
  const int h = (tid >> 5) & 1;
  const size_t qpA = (size_t)b * NT + qoff + qblk * 256 + w * 64 + cl;
  const size_t qpB = qpA + 32;
  const size_t cb0 = (size_t)b * NT + coff;

  for (int i = tid; i < 4096; i += 256) cnl[i] = norms[cb0 + i];

  const s16x8* cv = (const s16x8*)cbt;
  s16x8 bhA[8], blA[8], bhB[8], blB[8];
#pragma unroll
  for (int s = 0; s < 8; ++s) {
    bhA[s] = cv[(size_t)(2 * s + h) * 32768 + qpA];
    blA[s] = cv[(size_t)(16 + 2 * s + h) * 32768 + qpA];
    bhB[s] = cv[(size_t)(2 * s + h) * 32768 + qpB];
    blB[s] = cv[(size_t)(16 + 2 * s + h) * 32768 + qpB];
  }

  float bdA[12], bdB[12]; int biA[12], biB[12];
#pragma unroll
  for (int j = 0; j < 12; ++j) { bdA[j] = FLT_MAX; bdB[j] = FLT_MAX; biA[j] = 0; biB[j] = 0; }

  const int su = tid >> 5;
  const int sc = tid & 31;
  uint4 st[4];
  {
    size_t cp = cb0 + sc;
#pragma unroll
    for (int k = 0; k < 4; ++k)
      st[k] = *(const uint4*)&cbt[((size_t)(k * 8 + su) * 32768 + cp) * 8];
#pragma unroll
    for (int k = 0; k < 4; ++k)
      *(uint4*)&cst[0][k * 8 + su][sc][0] = st[k];
  }
  __syncthreads();

  int buf = 0;
  for (int t = 0; t < 128; ++t) {
    if (t < 127) {
      size_t cp = cb0 + (t + 1) * 32 + sc;
#pragma unroll
      for (int k = 0; k < 4; ++k)
        st[k] = *(const uint4*)&cbt[((size_t)(k * 8 + su) * 32768 + cp) * 8];
    }
    f32x16 accA = {0.f,0.f,0.f,0.f,0.f,0.f,0.f,0.f,0.f,0.f,0.f,0.f,0.f,0.f,0.f,0.f};
    f32x16 accB = {0.f,0.f,0.f,0.f,0.f,0.f,0.f,0.f,0.f,0.f,0.f,0.f,0.f,0.f,0.f,0.f};
#pragma unroll
    for (int s = 0; s < 8; ++s) {
      s16x8 a = *(const s16x8*)&cst[buf][2 * s + h][cl][0];
      accA = __builtin_amdgcn_mfma_f32_32x32x16_bf16(a, bhA[s], accA, 0, 0, 0);
      accB = __builtin_amdgcn_mfma_f32_32x32x16_bf16(a, bhB[s], accB, 0, 0, 0);
      accA = __builtin_amdgcn_mfma_f32_32x32x16_bf16(a, blA[s], accA, 0, 0, 0);
      accB = __builtin_amdgcn_mfma_f32_32x32x16_bf16(a, blB[s], accB, 0, 0, 0);
    }
#pragma unroll
    for (int s = 0; s < 8; ++s) {
      s16x8 a = *(const s16x8*)&cst[buf][16 + 2 * s + h][cl][0];
      accA = __builtin_amdgcn_mfma_f32_32x32x16_bf16(a, bhA[s], accA, 0, 0, 0);
      accB = __builtin_amdgcn_mfma_f32_32x32x16_bf16(a, bhB[s], accB, 0, 0, 0);
    }
    const int cbase = t * 32;
#pragma unroll
    for (int r = 0; r < 16; ++r) {
      const int crow = (r & 3) + 8 * (r >> 2) + 4 * h;
      const float cn = cnl[cbase + crow];
      const int idx = cbase + crow;
      float sA = fmaf(-2.0f, accA[r], cn);
      if (sA < bdA[11]) INSERT12(bdA, biA, sA, idx);
      float sB = fmaf(-2.0f, accB[r], cn);
      if (sB < bdB[11]) INSERT12(bdB, biB, sB, idx);
    }
    if (t < 127) {
#pragma unroll
      for (int k = 0; k < 4; ++k)
        *(uint4*)&cst[buf ^ 1][k * 8 + su][sc][0] = st[k];
    }
    __syncthreads();
    buf ^= 1;
  }

  const int qA = qblk * 256 + w * 64 + cl, qB = qA + 32;
  size_t baseA = ((size_t)(z * 4096 + qA) * 2 + h) * 12;
  size_t baseB = ((size_t)(z * 4096 + qB) * 2 + h) * 12;
#pragma unroll
  for (int j = 0; j < 12; ++j) {
    plD[baseA + j] = bdA[j]; plI[baseA + j] = (unsigned short)biA[j];
    plD[baseB + j] = bdB[j]; plI[baseB + j] = (unsigned short)biB[j];
  }
}

// ---------------- rerank: gap-guarded exact top-9 of the 24 shortlisted cands
// Common path (approx gap at the 9/10 boundary > GAP): approx set == exact set,
// write it. Rare path: recompute all 24 distances with round-1's exact fp32
// chain (sequential fmaf, same expression) and rank by (d, idx).
__global__ __launch_bounds__(256) void rerank_k(const float* __restrict__ xy,
                                                const float* __restrict__ norms,
                                                const float* __restrict__ plD,
                                                const unsigned short* __restrict__ plI,
                                                int* __restrict__ nbr) {
  const int lane = threadIdx.x & 63;
  const int gw = blockIdx.x * 4 + (threadIdx.x >> 6);  // 0..65535
  const int z = gw >> 12, q = gw & 4095;
  const int b = z >> 2, combo = z & 3;
  const int qoff = (combo <= 1) ? 0 : N1;
  const int coff = (combo == 0 || combo == 3) ? 0 : N1;
  const size_t cb0 = (size_t)b * NT + coff;

  const int row = (combo <= 1) ? q : (N1 + q);
  const int slot = (combo == 0 || combo == 2) ? 0 : 9;
  const int ioff = (combo == 1 || combo == 2) ? N1 : 0;
  int* dst = nbr + ((size_t)b * NT + row) * NBRS + slot;

  size_t pbase = (size_t)(z * 4096 + q) * 24;
  float d = FLT_MAX; int ci = 0;
  if (lane < 24) {
    d = plD[pbase + lane];
    ci = (int)plI[pbase + lane];
  }
  // rank among 24 by (approx d, idx)
  int rank = 0;
#pragma unroll 1
  for (int k = 0; k < 24; ++k) {
    float dk = __shfl(d, k); int ik = __shfl(ci, k);
    rank += ((dk < d) || (dk == d && ik < ci)) ? 1 : 0;
  }
  unsigned long long m8 = __ballot(lane < 24 && rank == 8);
  unsigned long long m9 = __ballot(lane < 24 && rank == 9);
  int l8 = __ffsll((unsigned long long)m8) - 1;
  int l9 = __ffsll((unsigned long long)m9) - 1;
  float d8 = __shfl(d, l8), d9 = __shfl(d, l9);

  if (d9 - d8 > GAP) {
    if (lane < 24 && rank < 9) dst[rank] = ci + ioff;
  } else {
    // exact path, round-1 arithmetic
    const int cis = (lane < 24) ? ci : 0;
    const float* qrow = xy + ((size_t)b * NT + qoff + q) * CH;
    const float* crow = xy + (cb0 + cis) * CH;
    const float cnv = norms[cb0 + cis];
    float a0 = 0.f, a1 = 0.f, a2 = 0.f, a3 = 0.f;
#pragma unroll
    for (int k = 0; k < 32; ++k) {
      float4 qv = *(const float4*)(qrow + k * 4);
      float4 cv2 = *(const float4*)(crow + k * 4);
      a0 = fmaf(qv.x, cv2.x, a0);
      a1 = fmaf(qv.y, cv2.y, a1);
      a2 = fmaf(qv.z, cv2.z, a2);
      a3 = fmaf(qv.w, cv2.w, a3);
    }
    float de = cnv - 2.0f * ((a0 + a1) + (a2 + a3));
    if (lane >= 24) de = FLT_MAX;
    int xr = 0;
#pragma unroll 1
    for (int k = 0; k < 24; ++k) {
      float dk = __shfl(de, k); int ik = __shfl(ci, k);
      xr += ((dk < de) || (dk == de && ik < ci)) ? 1 : 0;
    }
    if (lane < 24 && xr < 9) dst[xr] = ci + ioff;
  }
}

// ------------------------------------------- mrconv: gather+max+linear+BN+gelu
__global__ __launch_bounds__(256) void mrconv_k(const float* __restrict__ in,
                                                const int* __restrict__ nbr,
                                                const float* __restrict__ Wt,
                                                const float* __restrict__ bias,
                                                const float* __restrict__ gam,
                                                const float* __restrict__ bet,
                                                const float* __restrict__ mean,
                                                const float* __restrict__ var,
                                                float* __restrict__ out) {
  __shared__ float h[32][260];
  const int tid = threadIdx.x;
  const int pt0 = blockIdx.x * 32;
  {
    const int w = tid >> 6, lane = tid & 63;
    for (int pp = 0; pp < 8; ++pp) {
      const int p = w * 8 + pp;
      const int n = pt0 + p;
      const int b = n >> 13;
      const float* frow = in + (size_t)n * CH;
      float2 f2 = *(const float2*)(frow + lane * 2);
      float mx = -FLT_MAX, my = -FLT_MAX;
      const int* nb = nbr + (size_t)n * NBRS;
      for (int j = 0; j < NBRS; ++j) {
        int idx = nb[j];
        const float* vrow = in + ((size_t)b * NT + idx) * CH;
        float2 v2 = *(const float2*)(vrow + lane * 2);
        mx = fmaxf(mx, v2.x - f2.x);
        my = fmaxf(my, v2.y - f2.y);
      }
      h[p][lane * 4 + 0] = f2.x; h[p][lane * 4 + 1] = mx;
      h[p][lane * 4 + 2] = f2.y; h[p][lane * 4 + 3] = my;
    }
  }
  __syncthreads();
  const int o = tid & 127, gg = tid >> 7;
  float acc[16];
#pragma unroll
  for (int p = 0; p < 16; ++p) acc[p] = 0.f;
  for (int k = 0; k < 256; k += 4) {
    float w0 = Wt[(k + 0) * CH + o], w1 = Wt[(k + 1) * CH + o];
    float w2 = Wt[(k + 2) * CH + o], w3 = Wt[(k + 3) * CH + o];
#pragma unroll
    for (int p = 0; p < 16; ++p) {
      float4 hv = *(const float4*)&h[gg * 16 + p][k];
      acc[p] = fmaf(hv.x, w0, acc[p]);
      acc[p] = fmaf(hv.y, w1, acc[p]);
      acc[p] = fmaf(hv.z, w2, acc[p]);
      acc[p] = fmaf(hv.w, w3, acc[p]);
    }
  }
  const float sc = gam[o] / sqrtf(var[o] + 1e-5f);
  const float bs = bias[o], mo = mean[o], be = bet[o];
#pragma unroll
  for (int p = 0; p < 16; ++p) {
    const int n = pt0 + gg * 16 + p;
    float hv = acc[p] + bs;
    float bn = (hv - mo) * sc + be;
    float gl = 0.5f * bn * (1.0f + erff(bn * 0.70710678118654752f));
    out[(size_t)n * CH + o] = gl + h[gg * 16 + p][2 * o];
  }
}

// -------------------------------------------------------- fc: linear+BN+res
__global__ __launch_bounds__(256) void fc_k(const float* __restrict__ in,
                                            const float* __restrict__ Wt,
                                            const float* __restrict__ bias,
                                            const float* __restrict__ gam,
                                            const float* __restrict__ bet,
                                            const float* __restrict__ mean,
                                            const float* __restrict__ var,
                                            const float* __restrict__ xres,
                                            const float* __restrict__ yres,
                                            float* __restrict__ out) {
  __shared__ float s[32][132];
  const int tid = threadIdx.x;
  const int pt0 = blockIdx.x * 32;
  {
    const int w = tid >> 6, lane = tid & 63;
    for (int pp = 0; pp < 8; ++pp) {
      const int p = w * 8 + pp, n = pt0 + p;
      float2 v = *(const float2*)(in + (size_t)n * CH + lane * 2);
      s[p][lane * 2] = v.x; s[p][lane * 2 + 1] = v.y;
    }
  }
  __syncthreads();
  const int o = tid & 127, gg = tid >> 7;
  float acc[16];
#pragma unroll
  for (int p = 0; p < 16; ++p) acc[p] = 0.f;
  for (int k = 0; k < 128; k += 4) {
    float w0 = Wt[(k + 0) * CH + o], w1 = Wt[(k + 1) * CH + o];
    float w2 = Wt[(k + 2) * CH + o], w3 = Wt[(k + 3) * CH + o];
#pragma unroll
    for (int p = 0; p < 16; ++p) {
      float4 hv = *(const float4*)&s[gg * 16 + p][k];
      acc[p] = fmaf(hv.x, w0, fmaf(hv.y, w1, fmaf(hv.z, w2, fmaf(hv.w, w3, acc[p]))));
    }
  }
  const float sc = gam[o] / sqrtf(var[o] + 1e-5f);
  const float bs = bias[o], mo = mean[o], be = bet[o];
#pragma unroll
  for (int p = 0; p < 16; ++p) {
    const int n = pt0 + gg * 16 + p;
    const int b = n >> 13, row = n & 8191;
    float bn = (acc[p] + bs - mo) * sc + be;
    float res = (row < N1) ? xres[((size_t)b * N1 + row) * CH + o]
                           : yres[((size_t)b * N1 + row - N1) * CH + o];
    out[(size_t)n * CH + o] = bn + res;
  }
}

// ----------------------------------------------- ffn: 128->512->128 fused
__global__ __launch_bounds__(256) void ffn_k(const float* __restrict__ u,
                                             const float* __restrict__ W1t,
                                             const float* __restrict__ b1,
                                             const float* __restrict__ g1,
                                             const float* __restrict__ be1,
                                             const float* __restrict__ m1,
                                             const float* __restrict__ v1,
                                             const float* __restrict__ W2t,
                                             const float* __restrict__ b2,
                                             const float* __restrict__ g2,
                                             const float* __restrict__ be2,
                                             const float* __restrict__ m2,
                                             const float* __restrict__ v2,
                                             const float* __restrict__ xmask,
                                             const float* __restrict__ ymask,
                                             float* __restrict__ outbuf) {
  __shared__ float su[16][132];
  __shared__ float h1[16][516];
  const int tid = threadIdx.x;
  const int pt0 = blockIdx.x * 16;
  {
    const int w = tid >> 6, lane = tid & 63;
    for (int pp = 0; pp < 4; ++pp) {
      const int p = w * 4 + pp, n = pt0 + p;
      float2 v = *(const float2*)(u + (size_t)n * CH + lane * 2);
      su[p][lane * 2] = v.x; su[p][lane * 2 + 1] = v.y;
    }
  }
  __syncthreads();
  {
    const int o2 = tid;
    float a1[16], a2[16];
#pragma unroll
    for (int p = 0; p < 16; ++p) { a1[p] = 0.f; a2[p] = 0.f; }
    for (int k = 0; k < 128; k += 2) {
      float wA0 = W1t[(k + 0) * 512 + o2], wB0 = W1t[(k + 0) * 512 + o2 + 256];
      float wA1 = W1t[(k + 1) * 512 + o2], wB1 = W1t[(k + 1) * 512 + o2 + 256];
#pragma unroll
      for (int p = 0; p < 16; ++p) {
        float2 uv = *(const float2*)&su[p][k];
        a1[p] = fmaf(uv.x, wA0, fmaf(uv.y, wA1, a1[p]));
        a2[p] = fmaf(uv.x, wB0, fmaf(uv.y, wB1, a2[p]));
      }
    }
    float scA = g1[o2] / sqrtf(v1[o2] + 1e-5f);
    float scB = g1[o2 + 256] / sqrtf(v1[o2 + 256] + 1e-5f);
    float bsA = b1[o2], moA = m1[o2], beA = be1[o2];
    float bsB = b1[o2 + 256], moB = m1[o2 + 256], beB = be1[o2 + 256];
#pragma unroll
    for (int p = 0; p < 16; ++p) {
      float hA = (a1[p] + bsA - moA) * scA + beA;
      float hB = (a2[p] + bsB - moB) * scB + beB;
      h1[p][o2] = 0.5f * hA * (1.0f + erff(hA * 0.70710678118654752f));
      h1[p][o2 + 256] = 0.5f * hB * (1.0f + erff(hB * 0.70710678118654752f));
    }
  }
  __syncthreads();
  const int o = tid & 127, gg = tid >> 7;
  float acc[8];
#pragma unroll
  for (int p = 0; p < 8; ++p) acc[p] = 0.f;
  for (int k = 0; k < 512; k += 4) {
    float w0 = W2t[(k + 0) * CH + o], w1 = W2t[(k + 1) * CH + o];
    float w2 = W2t[(k + 2) * CH + o], w3 = W2t[(k + 3) * CH + o];
#pragma unroll
    for (int p = 0; p < 8; ++p) {
      float4 hv = *(const float4*)&h1[gg * 8 + p][k];
      acc[p] = fmaf(hv.x, w0, fmaf(hv.y, w1, fmaf(hv.z, w2, fmaf(hv.w, w3, acc[p]))));
    }
  }
  const float sc = g2[o] / sqrtf(v2[o] + 1e-5f);
  const float bs = b2[o], mo = m2[o], be = be2[o];
#pragma unroll
  for (int p = 0; p < 8; ++p) {
    const int n = pt0 + gg * 8 + p;
    const int b = n >> 13, row = n & 8191;
    float bn = (acc[p] + bs - mo) * sc + be;
    float gl = 0.5f * bn * (1.0f + erff(bn * 0.70710678118654752f));
    float res = su[gg * 8 + p][o];
    float msk; size_t oidx;
    if (row < N1) {
      msk = xmask[(size_t)b * N1 + row];
      oidx = ((size_t)b * N1 + row) * CH + o;
    } else {
      msk = ymask[(size_t)b * N1 + row - N1];
      oidx = (size_t)BB * N1 * CH + ((size_t)b * N1 + row - N1) * CH + o;
    }
    outbuf[oidx] = (gl + res) * msk;
  }
}

// ---------------------------------------------------------------------------
extern "C" void kernel_launch(void* const* d_in, const int* in_sizes, int n_in,
                              void* d_out, int out_size, void* d_ws, size_t ws_size,
                              hipStream_t stream) {
  const float* x  = (const float*)d_in[0];
  const float* y  = (const float*)d_in[1];
  const float* xm = (const float*)d_in[2];
  const float* ym = (const float*)d_in[3];
  const float* mr0W = (const float*)d_in[4];
  const float* mr1W = (const float*)d_in[10];
  const float* fcW  = (const float*)d_in[16];
  const float* f1W  = (const float*)d_in[22];
  const float* f2W  = (const float*)d_in[28];

  char* ws = (char*)d_ws;
  float*          xyA   = (float*)(ws + 0);            // 16 MB (lives whole run)
  unsigned short* cbt   = (unsigned short*)(ws + 16777216);  // 16 MB (dead after knn2)
  float*          xyB   = (float*)(ws + 16777216);     // alias over cbt (used after rerank)
  float*          norms = (float*)(ws + 33554432);     // 128 KB
  float*          plD   = (float*)(ws + 33685504);     // 6.29 MB
  unsigned short* plI   = (unsigned short*)(ws + 39976960);  // 3.15 MB
  int*            nbr   = (int*)(ws + 43122688);       // 2.36 MB
  float*          mr0t  = (float*)(ws + 45481984);
  float*          mr1t  = (float*)(ws + 45613056);
  float*          fct   = (float*)(ws + 45744128);
  float*          f1t   = (float*)(ws + 45809664);
  float*          f2t   = (float*)(ws + 46071808);

  transpose_k<<<(128 * 256 + 255) / 256, 256, 0, stream>>>(mr0W, mr0t, 128, 256);
  transpose_k<<<(128 * 256 + 255) / 256, 256, 0, stream>>>(mr1W, mr1t, 128, 256);
  transpose_k<<<(128 * 128 + 255) / 256, 256, 0, stream>>>(fcW, fct, 128, 128);
  transpose_k<<<(512 * 128 + 255) / 256, 256, 0, stream>>>(f1W, f1t, 512, 128);
  transpose_k<<<(128 * 512 + 255) / 256, 256, 0, stream>>>(f2W, f2t, 128, 512);

  norms_concat_k<<<8192, 256, 0, stream>>>(x, y, xyA, norms);
  cbt_k<<<2048, 256, 0, stream>>>(xyA, cbt);
  knn2_k<<<dim3(16, 16), 256, 0, stream>>>(cbt, norms, plD, plI);
  rerank_k<<<16384, 256, 0, stream>>>(xyA, norms, plD, plI, nbr);

  mrconv_k<<<1024, 256, 0, stream>>>(xyA, nbr, mr0t,
      (const float*)d_in[5], (const float*)d_in[6], (const float*)d_in[7],
      (const float*)d_in[8], (const float*)d_in[9], xyB);
  mrconv_k<<<1024, 256, 0, stream>>>(xyB, nbr, mr1t,
      (const float*)d_in[11], (const float*)d_in[12], (const float*)d_in[13],
      (const float*)d_in[14], (const float*)d_in[15], xyA);

  fc_k<<<1024, 256, 0, stream>>>(xyA, fct,
      (const float*)d_in[17], (const float*)d_in[18], (const float*)d_in[19],
      (const float*)d_in[20], (const float*)d_in[21], x, y, xyB);

  ffn_k<<<2048, 256, 0, stream>>>(xyB,
      f1t, (const float*)d_in[23], (const float*)d_in[24], (const float*)d_in[25],
      (const float*)d_in[26], (const float*)d_in[27],
      f2t, (const float*)d_in[29], (const float*)d_in[30], (const float*)d_in[31],
      (const float*)d_in[32], (const float*)d_in[33],
      xm, ym, (float*)d_out);
}

// Round 4
// 817.180 us; speedup vs baseline: 2.6317x; 1.9421x over previous
//
#include <hip/hip_runtime.h>
#include <hip/hip_bf16.h>
#include <float.h>
#include <math.h>

#define BB 4
#define N1 4096
#define NT 8192
#define CH 128
#define NBRS 18
#define GAP 2.0e-2f
#define KL 10          // per-partition shortlist depth
#define NLIST 20       // 2 partitions * KL

typedef __attribute__((ext_vector_type(8))) short s16x8;
typedef __attribute__((ext_vector_type(16))) float f32x16;

__device__ inline unsigned short f2bf(float v) {
  unsigned u = __float_as_uint(v);
  unsigned r = (u + 0x7FFFu + ((u >> 16) & 1u)) >> 16;
  return (unsigned short)r;
}

// ---------------------------------------------------------------- transpose
__global__ __launch_bounds__(256) void transpose_k(const float* __restrict__ in,
                                                   float* __restrict__ out,
                                                   int rows, int cols) {
  int t = blockIdx.x * 256 + threadIdx.x;
  if (t < rows * cols) {
    int r = t / cols, c = t % cols;
    out[c * rows + r] = in[t];
  }
}

// ------------------------------------------------- concat x,y + squared norms
__global__ __launch_bounds__(256) void norms_concat_k(const float* __restrict__ x,
                                                      const float* __restrict__ y,
                                                      float* __restrict__ xy,
                                                      float* __restrict__ norms) {
  int w = (blockIdx.x * 256 + threadIdx.x) >> 6;  // global point id, 0..32767
  int lane = threadIdx.x & 63;
  int b = w >> 13, row = w & 8191;
  const float* src = (row < N1) ? (x + ((size_t)b * N1 + row) * CH)
                                : (y + ((size_t)b * N1 + (row - N1)) * CH);
  float2 v = *(const float2*)(src + lane * 2);
  *(float2*)(xy + (size_t)w * CH + lane * 2) = v;
  float s = v.x * v.x + v.y * v.y;
  for (int off = 32; off > 0; off >>= 1) s += __shfl_down(s, off);
  if (lane == 0) norms[w] = s;
}

// ---------------------------------------- build split-bf16 k-major candidate buf
__global__ __launch_bounds__(256) void cbt_k(const float* __restrict__ xy,
                                             unsigned short* __restrict__ cbt) {
  int t = blockIdx.x * 256 + threadIdx.x;  // 32768*16
  int u = t >> 15, p = t & 32767;
  const float* src = xy + (size_t)p * CH + u * 8;
  unsigned hw[4], lw[4];
#pragma unroll
  for (int j = 0; j < 4; ++j) {
    float v0 = src[2 * j], v1 = src[2 * j + 1];
    unsigned short h0 = f2bf(v0), h1 = f2bf(v1);
    float r0 = v0 - __uint_as_float((unsigned)h0 << 16);
    float r1 = v1 - __uint_as_float((unsigned)h1 << 16);
    unsigned short l0 = f2bf(r0), l1 = f2bf(r1);
    hw[j] = (unsigned)h0 | ((unsigned)h1 << 16);
    lw[j] = (unsigned)l0 | ((unsigned)l1 << 16);
  }
  *(uint4*)&cbt[((size_t)u * 32768 + p) * 8] = make_uint4(hw[0], hw[1], hw[2], hw[3]);
  *(uint4*)&cbt[((size_t)(u + 16) * 32768 + p) * 8] = make_uint4(lw[0], lw[1], lw[2], lw[3]);
}

#define INSERT10(bd, bi, nd0, ni0)                        \
  {                                                       \
    float nd = nd0; int ni = ni0;                         \
    _Pragma("unroll")                                     \
    for (int j = 0; j < KL; ++j) {                        \
      bool sw = nd < bd[j];                               \
      float td = bd[j]; int ti = bi[j];                   \
      bd[j] = sw ? nd : td; bi[j] = sw ? ni : ti;         \
      nd = sw ? td : nd; ni = sw ? ti : ni;               \
    }                                                     \
  }

// ------------------------------------------------ MFMA knn: approx top-10 x 2
// grid (32 qblk, 16 z), block 256 = 4 waves; wave owns ONE 32-query tile.
// Candidates stream 32/chunk through dbuf LDS (shared by all 4 waves).
__global__ __launch_bounds__(256) void knn2_k(const unsigned short* __restrict__ cbt,
                                              const float* __restrict__ norms,
                                              float* __restrict__ plD,
                                              unsigned short* __restrict__ plI) {
  __shared__ unsigned short __align__(16) cst[2][32][32][8];
  __shared__ float cn_s[2][32];
  const int tid = threadIdx.x;
  const int qblk = blockIdx.x, z = blockIdx.y;
  const int b = z >> 2, combo = z & 3;
  const int qoff = (combo <= 1) ? 0 : N1;
  const int coff = (combo == 0 || combo == 3) ? 0 : N1;
  const int w = tid >> 6;
  const int cl = tid & 31;       // query within tile
  const int h = (tid >> 5) & 1;  // candidate-row partition
  const int h4 = 4 * h;
  const int q = qblk * 128 + w * 32 + cl;
  const size_t qp = (size_t)b * NT + qoff + q;
  const size_t cb0 = (size_t)b * NT + coff;

  // B-fragments: 8 hi + 8 lo units of this lane's query
  const s16x8* cv = (const s16x8*)cbt;
  s16x8 bh[8], bl[8];
#pragma unroll
  for (int s = 0; s < 8; ++s) {
    bh[s] = cv[(size_t)(2 * s + h) * 32768 + qp];
    bl[s] = cv[(size_t)(16 + 2 * s + h) * 32768 + qp];
  }

  float bd[KL]; int bi[KL];
#pragma unroll
  for (int j = 0; j < KL; ++j) { bd[j] = FLT_MAX; bi[j] = 0; }

  // staging pointers (4 rows of 8 units each), advance 512B per chunk
  const int su = tid >> 5;   // 0..7
  const int sc = tid & 31;
  const char* p0 = (const char*)&cbt[((size_t)(su) * 32768 + cb0 + sc) * 8];
  const char* p1 = (const char*)&cbt[((size_t)(8 + su) * 32768 + cb0 + sc) * 8];
  const char* p2 = (const char*)&cbt[((size_t)(16 + su) * 32768 + cb0 + sc) * 8];
  const char* p3 = (const char*)&cbt[((size_t)(24 + su) * 32768 + cb0 + sc) * 8];
  const float* pn = norms + cb0 + tid;  // valid when tid<32

  uint4 st[4];
  float cnreg;
  {
    st[0] = *(const uint4*)p0; p0 += 512;
    st[1] = *(const uint4*)p1; p1 += 512;
    st[2] = *(const uint4*)p2; p2 += 512;
    st[3] = *(const uint4*)p3; p3 += 512;
    if (tid < 32) cnreg = *pn;
    *(uint4*)&cst[0][su][sc][0] = st[0];
    *(uint4*)&cst[0][8 + su][sc][0] = st[1];
    *(uint4*)&cst[0][16 + su][sc][0] = st[2];
    *(uint4*)&cst[0][24 + su][sc][0] = st[3];
    if (tid < 32) { cn_s[0][tid] = cnreg; pn += 32; }
  }
  __syncthreads();

  int buf = 0;
  for (int t = 0; t < 128; ++t) {
    if (t < 127) {
      st[0] = *(const uint4*)p0; p0 += 512;
      st[1] = *(const uint4*)p1; p1 += 512;
      st[2] = *(const uint4*)p2; p2 += 512;
      st[3] = *(const uint4*)p3; p3 += 512;
      if (tid < 32) { cnreg = *pn; pn += 32; }
    }
    f32x16 acc = {0.f,0.f,0.f,0.f,0.f,0.f,0.f,0.f,0.f,0.f,0.f,0.f,0.f,0.f,0.f,0.f};
#pragma unroll
    for (int s = 0; s < 8; ++s) {
      s16x8 a0 = *(const s16x8*)&cst[buf][2 * s + h][cl][0];
      s16x8 a1 = *(const s16x8*)&cst[buf][16 + 2 * s + h][cl][0];
      acc = __builtin_amdgcn_mfma_f32_32x32x16_bf16(a0, bh[s], acc, 0, 0, 0);
      acc = __builtin_amdgcn_mfma_f32_32x32x16_bf16(a0, bl[s], acc, 0, 0, 0);
      acc = __builtin_amdgcn_mfma_f32_32x32x16_bf16(a1, bh[s], acc, 0, 0, 0);
    }
    // scores for the 16 candidate rows this lane covers
    float sv[16];
#pragma unroll
    for (int r = 0; r < 16; ++r) {
      const int crow_c = (r & 3) + 8 * (r >> 2);
      sv[r] = fmaf(-2.0f, acc[r], cn_s[buf][crow_c + h4]);
    }
    float m01 = fminf(sv[0], sv[1]),  m23 = fminf(sv[2], sv[3]);
    float m45 = fminf(sv[4], sv[5]),  m67 = fminf(sv[6], sv[7]);
    float m89 = fminf(sv[8], sv[9]),  mab = fminf(sv[10], sv[11]);
    float mcd = fminf(sv[12], sv[13]), mef = fminf(sv[14], sv[15]);
    float mA = fminf(fminf(m01, m23), fminf(m45, m67));
    float mB = fminf(fminf(m89, mab), fminf(mcd, mef));
    float mall = fminf(mA, mB);
    if (mall < bd[KL - 1]) {
      const int cb_h = t * 32 + h4;
#pragma unroll
      for (int r = 0; r < 16; ++r) {
        const int crow_c = (r & 3) + 8 * (r >> 2);
        if (sv[r] < bd[KL - 1]) INSERT10(bd, bi, sv[r], cb_h + crow_c);
      }
    }
    if (t < 127) {
      *(uint4*)&cst[buf ^ 1][su][sc][0] = st[0];
      *(uint4*)&cst[buf ^ 1][8 + su][sc][0] = st[1];
      *(uint4*)&cst[buf ^ 1][16 + su][sc][0] = st[2];
      *(uint4*)&cst[buf ^ 1][24 + su][sc][0] = st[3];
      if (tid < 32) cn_s[buf ^ 1][tid] = cnreg;
    }
    __syncthreads();
    buf ^= 1;
  }

  size_t base = ((size_t)(z * 4096 + q) * 2 + h) * KL;
#pragma unroll
  for (int j = 0; j < KL; ++j) {
    plD[base + j] = bd[j]; plI[base + j] = (unsigned short)bi[j];
  }
}

// ---------------- rerank: gap-guarded exact top-9 of the 20 shortlisted cands
__global__ __launch_bounds__(256) void rerank_k(const float* __restrict__ xy,
                                                const float* __restrict__ norms,
                                                const float* __restrict__ plD,
                                                const unsigned short* __restrict__ plI,
                                                int* __restrict__ nbr) {
  const int lane = threadIdx.x & 63;
  const int gw = blockIdx.x * 4 + (threadIdx.x >> 6);  // 0..65535
  const int z = gw >> 12, q = gw & 4095;
  const int b = z >> 2, combo = z & 3;
  const int qoff = (combo <= 1) ? 0 : N1;
  const int coff = (combo == 0 || combo == 3) ? 0 : N1;
  const size_t cb0 = (size_t)b * NT + coff;

  const int row = (combo <= 1) ? q : (N1 + q);
  const int slot = (combo == 0 || combo == 2) ? 0 : 9;
  const int ioff = (combo == 1 || combo == 2) ? N1 : 0;
  int* dst = nbr + ((size_t)b * NT + row) * NBRS + slot;

  size_t pbase = (size_t)(z * 4096 + q) * NLIST;
  float d = FLT_MAX; int ci = 0;
  if (lane < NLIST) {
    d = plD[pbase + lane];
    ci = (int)plI[pbase + lane];
  }
  // rank among NLIST by (approx d, idx)
  int rank = 0;
#pragma unroll 1
  for (int k = 0; k < NLIST; ++k) {
    float dk = __shfl(d, k); int ik = __shfl(ci, k);
    rank += ((dk < d) || (dk == d && ik < ci)) ? 1 : 0;
  }
  unsigned long long m8 = __ballot(lane < NLIST && rank == 8);
  unsigned long long m9 = __ballot(lane < NLIST && rank == 9);
  int l8 = __ffsll((unsigned long long)m8) - 1;
  int l9 = __ffsll((unsigned long long)m9) - 1;
  float d8 = __shfl(d, l8), d9 = __shfl(d, l9);

  if (d9 - d8 > GAP) {
    if (lane < NLIST && rank < 9) dst[rank] = ci + ioff;
  } else {
    // exact path, round-1 arithmetic
    const int cis = (lane < NLIST) ? ci : 0;
    const float* qrow = xy + ((size_t)b * NT + qoff + q) * CH;
    const float* crow = xy + (cb0 + cis) * CH;
    const float cnv = norms[cb0 + cis];
    float a0 = 0.f, a1 = 0.f, a2 = 0.f, a3 = 0.f;
#pragma unroll
    for (int k = 0; k < 32; ++k) {
      float4 qv = *(const float4*)(qrow + k * 4);
      float4 cv2 = *(const float4*)(crow + k * 4);
      a0 = fmaf(qv.x, cv2.x, a0);
      a1 = fmaf(qv.y, cv2.y, a1);
      a2 = fmaf(qv.z, cv2.z, a2);
      a3 = fmaf(qv.w, cv2.w, a3);
    }
    float de = cnv - 2.0f * ((a0 + a1) + (a2 + a3));
    if (lane >= NLIST) de = FLT_MAX;
    int xr = 0;
#pragma unroll 1
    for (int k = 0; k < NLIST; ++k) {
      float dk = __shfl(de, k); int ik = __shfl(ci, k);
      xr += ((dk < de) || (dk == de && ik < ci)) ? 1 : 0;
    }
    if (lane < NLIST && xr < 9) dst[xr] = ci + ioff;
  }
}

// ------------------------------------------- mrconv: gather+max+linear+BN+gelu
__global__ __launch_bounds__(256) void mrconv_k(const float* __restrict__ in,
                                                const int* __restrict__ nbr,
                                                const float* __restrict__ Wt,
                                                const float* __restrict__ bias,
                                                const float* __restrict__ gam,
                                                const float* __restrict__ bet,
                                                const float* __restrict__ mean,
                                                const float* __restrict__ var,
                                                float* __restrict__ out) {
  __shared__ float h[32][260];
  const int tid = threadIdx.x;
  const int pt0 = blockIdx.x * 32;
  {
    const int w = tid >> 6, lane = tid & 63;
    for (int pp = 0; pp < 8; ++pp) {
      const int p = w * 8 + pp;
      const int n = pt0 + p;
      const int b = n >> 13;
      const float* frow = in + (size_t)n * CH;
      float2 f2 = *(const float2*)(frow + lane * 2);
      float mx = -FLT_MAX, my = -FLT_MAX;
      const int* nb = nbr + (size_t)n * NBRS;
      for (int j = 0; j < NBRS; ++j) {
        int idx = nb[j];
        const float* vrow = in + ((size_t)b * NT + idx) * CH;
        float2 v2 = *(const float2*)(vrow + lane * 2);
        mx = fmaxf(mx, v2.x - f2.x);
        my = fmaxf(my, v2.y - f2.y);
      }
      h[p][lane * 4 + 0] = f2.x; h[p][lane * 4 + 1] = mx;
      h[p][lane * 4 + 2] = f2.y; h[p][lane * 4 + 3] = my;
    }
  }
  __syncthreads();
  const int o = tid & 127, gg = tid >> 7;
  float acc[16];
#pragma unroll
  for (int p = 0; p < 16; ++p) acc[p] = 0.f;
  for (int k = 0; k < 256; k += 4) {
    float w0 = Wt[(k + 0) * CH + o], w1 = Wt[(k + 1) * CH + o];
    float w2 = Wt[(k + 2) * CH + o], w3 = Wt[(k + 3) * CH + o];
#pragma unroll
    for (int p = 0; p < 16; ++p) {
      float4 hv = *(const float4*)&h[gg * 16 + p][k];
      acc[p] = fmaf(hv.x, w0, acc[p]);
      acc[p] = fmaf(hv.y, w1, acc[p]);
      acc[p] = fmaf(hv.z, w2, acc[p]);
      acc[p] = fmaf(hv.w, w3, acc[p]);
    }
  }
  const float sc = gam[o] / sqrtf(var[o] + 1e-5f);
  const float bs = bias[o], mo = mean[o], be = bet[o];
#pragma unroll
  for (int p = 0; p < 16; ++p) {
    const int n = pt0 + gg * 16 + p;
    float hv = acc[p] + bs;
    float bn = (hv - mo) * sc + be;
    float gl = 0.5f * bn * (1.0f + erff(bn * 0.70710678118654752f));
    out[(size_t)n * CH + o] = gl + h[gg * 16 + p][2 * o];
  }
}

// -------------------------------------------------------- fc: linear+BN+res
__global__ __launch_bounds__(256) void fc_k(const float* __restrict__ in,
                                            const float* __restrict__ Wt,
                                            const float* __restrict__ bias,
                                            const float* __restrict__ gam,
                                            const float* __restrict__ bet,
                                            const float* __restrict__ mean,
                                            const float* __restrict__ var,
                                            const float* __restrict__ xres,
                                            const float* __restrict__ yres,
                                            float* __restrict__ out) {
  __shared__ float s[32][132];
  const int tid = threadIdx.x;
  const int pt0 = blockIdx.x * 32;
  {
    const int w = tid >> 6, lane = tid & 63;
    for (int pp = 0; pp < 8; ++pp) {
      const int p = w * 8 + pp, n = pt0 + p;
      float2 v = *(const float2*)(in + (size_t)n * CH + lane * 2);
      s[p][lane * 2] = v.x; s[p][lane * 2 + 1] = v.y;
    }
  }
  __syncthreads();
  const int o = tid & 127, gg = tid >> 7;
  float acc[16];
#pragma unroll
  for (int p = 0; p < 16; ++p) acc[p] = 0.f;
  for (int k = 0; k < 128; k += 4) {
    float w0 = Wt[(k + 0) * CH + o], w1 = Wt[(k + 1) * CH + o];
    float w2 = Wt[(k + 2) * CH + o], w3 = Wt[(k + 3) * CH + o];
#pragma unroll
    for (int p = 0; p < 16; ++p) {
      float4 hv = *(const float4*)&s[gg * 16 + p][k];
      acc[p] = fmaf(hv.x, w0, fmaf(hv.y, w1, fmaf(hv.z, w2, fmaf(hv.w, w3, acc[p]))));
    }
  }
  const float sc = gam[o] / sqrtf(var[o] + 1e-5f);
  const float bs = bias[o], mo = mean[o], be = bet[o];
#pragma unroll
  for (int p = 0; p < 16; ++p) {
    const int n = pt0 + gg * 16 + p;
    const int b = n >> 13, row = n & 8191;
    float bn = (acc[p] + bs - mo) * sc + be;
    float res = (row < N1) ? xres[((size_t)b * N1 + row) * CH + o]
                           : yres[((size_t)b * N1 + row - N1) * CH + o];
    out[(size_t)n * CH + o] = bn + res;
  }
}

// ----------------------------------------------- ffn: 128->512->128 fused
__global__ __launch_bounds__(256) void ffn_k(const float* __restrict__ u,
                                             const float* __restrict__ W1t,
                                             const float* __restrict__ b1,
                                             const float* __restrict__ g1,
                                             const float* __restrict__ be1,
                                             const float* __restrict__ m1,
                                             const float* __restrict__ v1,
                                             const float* __restrict__ W2t,
                                             const float* __restrict__ b2,
                                             const float* __restrict__ g2,
                                             const float* __restrict__ be2,
                                             const float* __restrict__ m2,
                                             const float* __restrict__ v2,
                                             const float* __restrict__ xmask,
                                             const float* __restrict__ ymask,
                                             float* __restrict__ outbuf) {
  __shared__ float su[16][132];
  __shared__ float h1[16][516];
  const int tid = threadIdx.x;
  const int pt0 = blockIdx.x * 16;
  {
    const int w = tid >> 6, lane = tid & 63;
    for (int pp = 0; pp < 4; ++pp) {
      const int p = w * 4 + pp, n = pt0 + p;
      float2 v = *(const float2*)(u + (size_t)n * CH + lane * 2);
      su[p][lane * 2] = v.x; su[p][lane * 2 + 1] = v.y;
    }
  }
  __syncthreads();
  {
    const int o2 = tid;
    float a1[16], a2[16];
#pragma unroll
    for (int p = 0; p < 16; ++p) { a1[p] = 0.f; a2[p] = 0.f; }
    for (int k = 0; k < 128; k += 2) {
      float wA0 = W1t[(k + 0) * 512 + o2], wB0 = W1t[(k + 0) * 512 + o2 + 256];
      float wA1 = W1t[(k + 1) * 512 + o2], wB1 = W1t[(k + 1) * 512 + o2 + 256];
#pragma unroll
      for (int p = 0; p < 16; ++p) {
        float2 uv = *(const float2*)&su[p][k];
        a1[p] = fmaf(uv.x, wA0, fmaf(uv.y, wA1, a1[p]));
        a2[p] = fmaf(uv.x, wB0, fmaf(uv.y, wB1, a2[p]));
      }
    }
    float scA = g1[o2] / sqrtf(v1[o2] + 1e-5f);
    float scB = g1[o2 + 256] / sqrtf(v1[o2 + 256] + 1e-5f);
    float bsA = b1[o2], moA = m1[o2], beA = be1[o2];
    float bsB = b1[o2 + 256], moB = m1[o2 + 256], beB = be1[o2 + 256];
#pragma unroll
    for (int p = 0; p < 16; ++p) {
      float hA = (a1[p] + bsA - moA) * scA + beA;
      float hB = (a2[p] + bsB - moB) * scB + beB;
      h1[p][o2] = 0.5f * hA * (1.0f + erff(hA * 0.70710678118654752f));
      h1[p][o2 + 256] = 0.5f * hB * (1.0f + erff(hB * 0.70710678118654752f));
    }
  }
  __syncthreads();
  const int o = tid & 127, gg = tid >> 7;
  float acc[8];
#pragma unroll
  for (int p = 0; p < 8; ++p) acc[p] = 0.f;
  for (int k = 0; k < 512; k += 4) {
    float w0 = W2t[(k + 0) * CH + o], w1 = W2t[(k + 1) * CH + o];
    float w2 = W2t[(k + 2) * CH + o], w3 = W2t[(k + 3) * CH + o];
#pragma unroll
    for (int p = 0; p < 8; ++p) {
      float4 hv = *(const float4*)&h1[gg * 8 + p][k];
      acc[p] = fmaf(hv.x, w0, fmaf(hv.y, w1, fmaf(hv.z, w2, fmaf(hv.w, w3, acc[p]))));
    }
  }
  const float sc = g2[o] / sqrtf(v2[o] + 1e-5f);
  const float bs = b2[o], mo = m2[o], be = be2[o];
#pragma unroll
  for (int p = 0; p < 8; ++p) {
    const int n = pt0 + gg * 8 + p;
    const int b = n >> 13, row = n & 8191;
    float bn = (acc[p] + bs - mo) * sc + be;
    float gl = 0.5f * bn * (1.0f + erff(bn * 0.70710678118654752f));
    float res = su[gg * 8 + p][o];
    float msk; size_t oidx;
    if (row < N1) {
      msk = xmask[(size_t)b * N1 + row];
      oidx = ((size_t)b * N1 + row) * CH + o;
    } else {
      msk = ymask[(size_t)b * N1 + row - N1];
      oidx = (size_t)BB * N1 * CH + ((size_t)b * N1 + row - N1) * CH + o;
    }
    outbuf[oidx] = (gl + res) * msk;
  }
}

// ---------------------------------------------------------------------------
extern "C" void kernel_launch(void* const* d_in, const int* in_sizes, int n_in,
                              void* d_out, int out_size, void* d_ws, size_t ws_size,
                              hipStream_t stream) {
  const float* x  = (const float*)d_in[0];
  const float* y  = (const float*)d_in[1];
  const float* xm = (const float*)d_in[2];
  const float* ym = (const float*)d_in[3];
  const float* mr0W = (const float*)d_in[4];
  const float* mr1W = (const float*)d_in[10];
  const float* fcW  = (const float*)d_in[16];
  const float* f1W  = (const float*)d_in[22];
  const float* f2W  = (const float*)d_in[28];

  char* ws = (char*)d_ws;
  float*          xyA   = (float*)(ws + 0);                  // 16.78 MB
  unsigned short* cbt   = (unsigned short*)(ws + 16777216);  // 16.78 MB (dead after knn2)
  float*          xyB   = (float*)(ws + 16777216);           // alias over cbt
  float*          norms = (float*)(ws + 33554432);           // 128 KB
  float*          plD   = (float*)(ws + 33685504);           // 5.24 MB
  unsigned short* plI   = (unsigned short*)(ws + 38928384);  // 2.62 MB
  int*            nbr   = (int*)(ws + 41549824);             // 2.36 MB
  float*          mr0t  = (float*)(ws + 43909120);
  float*          mr1t  = (float*)(ws + 44040192);
  float*          fct   = (float*)(ws + 44171264);
  float*          f1t   = (float*)(ws + 44236800);
  float*          f2t   = (float*)(ws + 44498944);

  transpose_k<<<(128 * 256 + 255) / 256, 256, 0, stream>>>(mr0W, mr0t, 128, 256);
  transpose_k<<<(128 * 256 + 255) / 256, 256, 0, stream>>>(mr1W, mr1t, 128, 256);
  transpose_k<<<(128 * 128 + 255) / 256, 256, 0, stream>>>(fcW, fct, 128, 128);
  transpose_k<<<(512 * 128 + 255) / 256, 256, 0, stream>>>(f1W, f1t, 512, 128);
  transpose_k<<<(128 * 512 + 255) / 256, 256, 0, stream>>>(f2W, f2t, 128, 512);

  norms_concat_k<<<8192, 256, 0, stream>>>(x, y, xyA, norms);
  cbt_k<<<2048, 256, 0, stream>>>(xyA, cbt);
  knn2_k<<<dim3(32, 16), 256, 0, stream>>>(cbt, norms, plD, plI);
  rerank_k<<<16384, 256, 0, stream>>>(xyA, norms, plD, plI, nbr);

  mrconv_k<<<1024, 256, 0, stream>>>(xyA, nbr, mr0t,
      (const float*)d_in[5], (const float*)d_in[6], (const float*)d_in[7],
      (const float*)d_in[8], (const float*)d_in[9], xyB);
  mrconv_k<<<1024, 256, 0, stream>>>(xyB, nbr, mr1t,
      (const float*)d_in[11], (const float*)d_in[12], (const float*)d_in[13],
      (const float*)d_in[14], (const float*)d_in[15], xyA);

  fc_k<<<1024, 256, 0, stream>>>(xyA, fct,
      (const float*)d_in[17], (const float*)d_in[18], (const float*)d_in[19],
      (const float*)d_in[20], (const float*)d_in[21], x, y, xyB);

  ffn_k<<<2048, 256, 0, stream>>>(xyB,
      f1t, (const float*)d_in[23], (const float*)d_in[24], (const float*)d_in[25],
      (const float*)d_in[26], (const float*)d_in[27],
      f2t, (const float*)d_in[29], (const float*)d_in[30], (const float*)d_in[31],
      (const float*)d_in[32], (const float*)d_in[33],
      xm, ym, (float*)d_out);
}